// Round 1
// baseline (1232.064 us; speedup 1.0000x reference)
//
#include <hip/hip_runtime.h>

#define NPTS 1000000
#define KOFF 27
#define NWG_CONV 7813            // ceil(N/128)
#define NWAVES (NWG_CONV * 4)

typedef __bf16 bf16x8 __attribute__((ext_vector_type(8)));
typedef __bf16 bf16x4 __attribute__((ext_vector_type(4)));
typedef float f32x4 __attribute__((ext_vector_type(4)));

// ---------------- Kernel 1: xb[N+1][64] = bf16(concat(feats, time_emb[batch_idx])) ; row N = 0
__global__ __launch_bounds__(256) void build_x_kernel(
    const float* __restrict__ feats, const float* __restrict__ time_emb,
    const int* __restrict__ batch_idx, __bf16* __restrict__ xb)
{
    const long g = (long)blockIdx.x * 256 + threadIdx.x;
    if (g >= (long)(NPTS + 1) * 16) return;
    const int row = (int)(g >> 4);
    const int c = ((int)g & 15) << 2;
    bf16x4 o;
    if (row < NPTS) {
        f32x4 v;
        if (c < 32) {
            v = *(const f32x4*)(feats + (size_t)row * 32 + c);
        } else {
            const int b = batch_idx[row];
            v = *(const f32x4*)(time_emb + (size_t)b * 32 + (c - 32));
        }
        o[0] = (__bf16)v[0]; o[1] = (__bf16)v[1];
        o[2] = (__bf16)v[2]; o[3] = (__bf16)v[3];
    } else {
        o[0] = o[1] = o[2] = o[3] = (__bf16)0.0f;
    }
    *(bf16x4*)(xb + (size_t)row * 64 + c) = o;
}

// ---------------- Kernel 2: WbT[k][cout][cin] = bf16(W[k][cin][cout])
__global__ __launch_bounds__(256) void wtrans_kernel(
    const float* __restrict__ W, __bf16* __restrict__ wbt)
{
    const int g = blockIdx.x * 256 + threadIdx.x;
    if (g >= KOFF * 4096) return;
    const int k = g >> 12;
    const int rem = g & 4095;
    const int co = rem >> 6;
    const int ci = rem & 63;
    wbt[g] = (__bf16)W[(k << 12) + (ci << 6) + co];
}

// ---------------- Kernel 3: gather-GEMM conv. 4 waves/WG, no LDS, no barriers.
// wave owns 32 point-rows x 64 cols; A gathered straight into MFMA fragments.
__global__ __launch_bounds__(256) void conv_kernel(
    const __bf16* __restrict__ xb, const __bf16* __restrict__ wbt,
    const int* __restrict__ nbr_idx, const int* __restrict__ nbr_valid,
    float* __restrict__ out, float* __restrict__ partials)
{
    const int tid  = threadIdx.x;
    const int wave = tid >> 6;
    const int lane = tid & 63;
    const int l15  = lane & 15;
    const int quad = lane >> 4;
    const int wg   = blockIdx.x;
    const int R0   = wg * 128 + wave * 32;
    const int row0 = R0 + l15;        // A-fragment row for M-tile 0 (A row = lane&15)
    const int row1 = row0 + 16;       // M-tile 1

    f32x4 acc[2][4];
#pragma unroll
    for (int m = 0; m < 2; ++m)
#pragma unroll
        for (int ct = 0; ct < 4; ++ct)
            acc[m][ct] = (f32x4){0.f, 0.f, 0.f, 0.f};

    const int r0c = row0 < NPTS ? row0 : NPTS - 1;
    const int r1c = row1 < NPTS ? row1 : NPTS - 1;
    const bool ok0 = row0 < NPTS;
    const bool ok1 = row1 < NPTS;

    for (int k = 0; k < KOFF; ++k) {
        const int kb = k * NPTS;
        int i0 = nbr_idx[kb + r0c];
        int i1 = nbr_idx[kb + r1c];
        int v0 = nbr_valid[kb + r0c];
        int v1 = nbr_valid[kb + r1c];
        // invalid (or out-of-range tail row) -> gather the all-zero row N
        const int g0 = (v0 && ok0) ? i0 : NPTS;
        const int g1 = (v1 && ok1) ? i1 : NPTS;

        // B fragments: WbT chunk index = k*512 + (ct*16+l15)*8 + kk*4 + quad
        const bf16x8* wb8 = (const bf16x8*)wbt + (size_t)k * 512 + l15 * 8 + quad;
        bf16x8 b0[4], b1[4];
#pragma unroll
        for (int ct = 0; ct < 4; ++ct) {
            b0[ct] = wb8[ct * 128];       // kk = 0
            b1[ct] = wb8[ct * 128 + 4];   // kk = 1
        }

        // A fragments: row chunk = kk*4 + quad  (8 bf16 = 16B per lane)
        const bf16x8* a0p = (const bf16x8*)(xb + (size_t)g0 * 64) + quad;
        const bf16x8* a1p = (const bf16x8*)(xb + (size_t)g1 * 64) + quad;
        const bf16x8 a0lo = a0p[0], a0hi = a0p[4];
        const bf16x8 a1lo = a1p[0], a1hi = a1p[4];

#pragma unroll
        for (int ct = 0; ct < 4; ++ct) {
            acc[0][ct] = __builtin_amdgcn_mfma_f32_16x16x32_bf16(a0lo, b0[ct], acc[0][ct], 0, 0, 0);
            acc[0][ct] = __builtin_amdgcn_mfma_f32_16x16x32_bf16(a0hi, b1[ct], acc[0][ct], 0, 0, 0);
            acc[1][ct] = __builtin_amdgcn_mfma_f32_16x16x32_bf16(a1lo, b0[ct], acc[1][ct], 0, 0, 0);
            acc[1][ct] = __builtin_amdgcn_mfma_f32_16x16x32_bf16(a1hi, b1[ct], acc[1][ct], 0, 0, 0);
        }
    }

    // store pre-BN f32 to d_out: D layout col = lane&15, row = quad*4 + reg
#pragma unroll
    for (int m = 0; m < 2; ++m) {
        const int rbase = R0 + m * 16 + quad * 4;
#pragma unroll
        for (int j = 0; j < 4; ++j) {
            const int row = rbase + j;
            if (row < NPTS) {
#pragma unroll
                for (int ct = 0; ct < 4; ++ct)
                    out[(size_t)row * 64 + ct * 16 + l15] = acc[m][ct][j];
            }
        }
    }

    // per-wave BN partials (tail rows have acc==0 -> contribute nothing)
#pragma unroll
    for (int ct = 0; ct < 4; ++ct) {
        float s = 0.f, ss = 0.f;
#pragma unroll
        for (int m = 0; m < 2; ++m)
#pragma unroll
            for (int j = 0; j < 4; ++j) {
                const float v = acc[m][ct][j];
                s += v; ss += v * v;
            }
        s  += __shfl_xor(s, 16);  s  += __shfl_xor(s, 32);
        ss += __shfl_xor(ss, 16); ss += __shfl_xor(ss, 32);
        if (lane < 16) {
            const size_t pb = ((size_t)wg * 4 + wave) * 128;
            partials[pb + ct * 16 + lane]      = s;
            partials[pb + 64 + ct * 16 + lane] = ss;
        }
    }
}

// ---------------- Kernel 4: reduce partials [NWAVES][128] -> p2 [128][128]
__global__ __launch_bounds__(256) void bn_pass1(
    const float* __restrict__ partials, float* __restrict__ p2)
{
    __shared__ float lds[256];
    const int tid = threadIdx.x;
    const int c = tid & 127;
    const int half = tid >> 7;
    float s = 0.f;
    for (int r = blockIdx.x * 2 + half; r < NWAVES; r += 256)
        s += partials[(size_t)r * 128 + c];
    lds[tid] = s;
    __syncthreads();
    if (tid < 128) p2[blockIdx.x * 128 + tid] = lds[tid] + lds[tid + 128];
}

// ---------------- Kernel 5: finalize BN scale/shift (64 + 64 floats)
__global__ void bn_pass2(const float* __restrict__ p2, const float* __restrict__ gamma,
                         const float* __restrict__ beta, float* __restrict__ bn)
{
    __shared__ float lds[128];
    const int t = threadIdx.x;
    float s = 0.f;
    for (int b = 0; b < 128; ++b) s += p2[b * 128 + t];
    lds[t] = s;
    __syncthreads();
    if (t < 64) {
        const float inv_n = 1.0f / (float)NPTS;
        const float mean = lds[t] * inv_n;
        const float var = lds[t + 64] * inv_n - mean * mean;
        const float scale = rsqrtf(var + 1e-5f) * gamma[t];
        bn[t] = scale;
        bn[64 + t] = beta[t] - mean * scale;   // bias cancels under BN; omitted
    }
}

// ---------------- Kernel 6: y = silu(pre*scale + shift), in-place on d_out
__global__ __launch_bounds__(256) void bn_silu_kernel(
    float* __restrict__ out, const float* __restrict__ bn)
{
    __shared__ float s[128];
    if (threadIdx.x < 128) s[threadIdx.x] = bn[threadIdx.x];
    __syncthreads();
    f32x4* o4 = (f32x4*)out;
    const long M4 = (long)NPTS * 16;
    for (long i = (long)blockIdx.x * 256 + threadIdx.x; i < M4; i += (long)gridDim.x * 256) {
        const int c0 = ((int)i & 15) << 2;
        f32x4 v = o4[i];
#pragma unroll
        for (int j = 0; j < 4; ++j) {
            const float y = v[j] * s[c0 + j] + s[64 + c0 + j];
            v[j] = y * (1.0f / (1.0f + __expf(-y)));
        }
        o4[i] = v;
    }
}

extern "C" void kernel_launch(void* const* d_in, const int* in_sizes, int n_in,
                              void* d_out, int out_size, void* d_ws, size_t ws_size,
                              hipStream_t stream)
{
    const float* feats     = (const float*)d_in[0];
    const float* time_emb  = (const float*)d_in[1];
    const float* W         = (const float*)d_in[2];
    /* d_in[3] = bias: cancels exactly under training-mode BN -> unused */
    const float* gamma     = (const float*)d_in[4];
    const float* beta      = (const float*)d_in[5];
    const int*   batch_idx = (const int*)d_in[6];
    const int*   nbr_idx   = (const int*)d_in[7];
    const int*   nbr_valid = (const int*)d_in[8];
    float* out = (float*)d_out;

    char* ws = (char*)d_ws;
    size_t off = 0;
    __bf16* xb  = (__bf16*)(ws + off); off += (size_t)(NPTS + 1) * 64 * 2;   // 128.0 MB
    __bf16* wbt = (__bf16*)(ws + off); off += (size_t)KOFF * 4096 * 2;       // 216 KB
    float* partials = (float*)(ws + off); off += (size_t)NWAVES * 128 * 4;   // 16.0 MB
    float* p2   = (float*)(ws + off); off += 128 * 128 * 4;                  // 64 KB
    float* bn   = (float*)(ws + off); off += 512;

    hipLaunchKernelGGL(build_x_kernel, dim3(62501), dim3(256), 0, stream,
                       feats, time_emb, batch_idx, xb);
    hipLaunchKernelGGL(wtrans_kernel, dim3(432), dim3(256), 0, stream, W, wbt);
    hipLaunchKernelGGL(conv_kernel, dim3(NWG_CONV), dim3(256), 0, stream,
                       xb, wbt, nbr_idx, nbr_valid, out, partials);
    hipLaunchKernelGGL(bn_pass1, dim3(128), dim3(256), 0, stream, partials, p2);
    hipLaunchKernelGGL(bn_pass2, dim3(1), dim3(128), 0, stream, p2, gamma, beta, bn);
    hipLaunchKernelGGL(bn_silu_kernel, dim3(2048), dim3(256), 0, stream, out, bn);
}